// Round 5
// baseline (13341.049 us; speedup 1.0000x reference)
//
#include <hip/hip_runtime.h>

// np.float32(np.pi / 180)
#define PI180F 0.017453292519943295f

// ---------------------------------------------------------------------------
// Rotation matrix, matching the reference's (Rz @ Ry) @ Rx in fp32.
// ---------------------------------------------------------------------------
__device__ __forceinline__ void compute_R(const float th[6], float R[9], float t[3]) {
    float ax = th[0] * PI180F, ay = th[1] * PI180F, az = th[2] * PI180F;
    float cx = cosf(ax), sx = sinf(ax);
    float cy = cosf(ay), sy = sinf(ay);
    float cz = cosf(az), sz = sinf(az);
    R[0] = cz * cy;  R[1] = (cz * sy) * sx - sz * cx;  R[2] = (cz * sy) * cx + sz * sx;
    R[3] = sz * cy;  R[4] = (sz * sy) * sx + cz * cx;  R[5] = (sz * sy) * cx - cz * sx;
    R[6] = -sy;      R[7] = cy * sx;                   R[8] = cy * cx;
    t[0] = th[3]; t[1] = th[4]; t[2] = th[5];
}

// ---------------------------------------------------------------------------
// Trilinear sample on a zero-padded volume (side P=D+3) — round-4 proven,
// branch-free, bit-identical to the predicated reference form.
// ---------------------------------------------------------------------------
template<int D>
__device__ __forceinline__ float tri_sample_pad(const float* __restrict__ vol,
                                                float c0, float c1, float c2) {
    constexpr int P = D + 3;
    float f0 = floorf(c0), f1 = floorf(c1), f2 = floorf(c2);
    int i0 = (int)f0, i1 = (int)f1, i2 = (int)f2;
    float t0 = c0 - f0, t1 = c1 - f1, t2 = c2 - f2;
    float w0[2] = {1.0f - t0, t0};
    float w1[2] = {1.0f - t1, t1};
    float w2[2] = {1.0f - t2, t2};
    int ip0 = ((unsigned)(i0 + 1) <= (unsigned)D) ? (i0 + 1) : (D + 1);
    int ip1 = ((unsigned)(i1 + 1) <= (unsigned)D) ? (i1 + 1) : (D + 1);
    int ip2 = ((unsigned)(i2 + 1) <= (unsigned)D) ? (i2 + 1) : (D + 1);
    const float* p = vol + ((ip0 * P + ip1) * P + ip2);
    float acc = 0.0f;
    acc += ((w0[0] * w1[0]) * w2[0]) * p[0];
    acc += ((w0[0] * w1[0]) * w2[1]) * p[1];
    acc += ((w0[0] * w1[1]) * w2[0]) * p[P];
    acc += ((w0[0] * w1[1]) * w2[1]) * p[P + 1];
    acc += ((w0[1] * w1[0]) * w2[0]) * p[P * P];
    acc += ((w0[1] * w1[0]) * w2[1]) * p[P * P + 1];
    acc += ((w0[1] * w1[1]) * w2[0]) * p[P * P + P];
    acc += ((w0[1] * w1[1]) * w2[1]) * p[P * P + P + 1];
    return acc;
}

// ---------------------------------------------------------------------------
// Eval body (round-4 verbatim inner loop), returns block partial in red[0].
// ---------------------------------------------------------------------------
template<int D, int K>
__device__ __forceinline__ void eval_block(
    const float* __restrict__ srcp, const float* __restrict__ tgt,
    const float th[6], int b, int k, double* __restrict__ red)
{
    constexpr int logD = (D == 64) ? 6 : ((D == 32) ? 5 : 4);
    constexpr int n = D * D * D;
    constexpr int PS = (D + 3) * (D + 3) * (D + 3);
    float R[9], t[3];
    compute_R(th, R, t);

    constexpr int chunk = n / K;
    const int vstart = k * chunk;
    const float step = 2.0f / (float)(D - 1);
    const float scale = (float)(D - 1) * 0.5f;
    const float* s = srcp + (size_t)b * PS;
    const float* g = tgt + (size_t)b * n;

    double acc = 0.0;
    for (int v = vstart + threadIdx.x; v < vstart + chunk; v += 256) {
        int kk = v & (D - 1);
        int jj = (v >> logD) & (D - 1);
        int ii = v >> (2 * logD);
        float x0 = -1.0f + (float)ii * step;
        float x1 = -1.0f + (float)jj * step;
        float x2 = -1.0f + (float)kk * step;
        float p0 = R[0] * x0 + R[1] * x1 + R[2] * x2 + t[0];
        float p1 = R[3] * x0 + R[4] * x1 + R[5] * x2 + t[1];
        float p2 = R[6] * x0 + R[7] * x1 + R[8] * x2 + t[2];
        float c0 = (p0 + 1.0f) * scale;
        float c1 = (p1 + 1.0f) * scale;
        float c2 = (p2 + 1.0f) * scale;
        float w = tri_sample_pad<D>(s, c0, c1, c2);
        float d = w - g[v];
        acc += (double)(d * d);
    }

    red[threadIdx.x] = acc;
    __syncthreads();
#pragma unroll
    for (int st = 128; st > 0; st >>= 1) {
        if (threadIdx.x < st) red[threadIdx.x] += red[threadIdx.x + st];
        __syncthreads();
    }
}

// ---------------------------------------------------------------------------
// FD eval + fused update1 tail (last-block election).
// first=1: 13 configs (c=0..12); first=0: 12 configs (c=1..12, base carried).
// ---------------------------------------------------------------------------
template<int D, int K>
__global__ __launch_bounds__(256) void fd_kernel(
    const float* __restrict__ srcp, const float* __restrict__ tgt,
    const float* __restrict__ theta, float* __restrict__ ttry,
    float* __restrict__ mom, float* __restrict__ lcur, float* __restrict__ lall,
    const int* __restrict__ active,
    double* __restrict__ partials, int* __restrict__ counter,
    float ss, int first)
{
    constexpr int n = D * D * D;
    __shared__ double red[256];
    __shared__ float lossf[104];
    __shared__ int lastf;
    const int tid = threadIdx.x;
    const int gb = blockIdx.x;
    const int k = gb % K;
    const int e = gb / K;
    const int b = e & 7;
    const int c = first ? (e >> 3) : (e >> 3) + 1;

    if (active[b]) {
        float th[6];
#pragma unroll
        for (int j = 0; j < 6; ++j) th[j] = theta[b * 6 + j];
        if (c > 0) {
            int j = (c - 1) % 6;
            th[j] += (c <= 6) ? ss : -ss;
        }
        eval_block<D, K>(srcp, tgt, th, b, k, red);
        if (tid == 0) partials[(size_t)(c * 8 + b) * K + k] = red[0];
    }

    __threadfence();
    if (tid == 0) lastf = (atomicAdd(counter, 1) == (int)gridDim.x - 1) ? 1 : 0;
    __syncthreads();
    if (!lastf) return;
    if (tid == 0) *counter = 0;

    // ---- elected last block: update1 ----
    const int nc = first ? 13 : 12;
    if (tid < nc * 8) {
        int slot = first ? tid : tid + 8;
        double s = 0.0;
#pragma unroll
        for (int i = 0; i < K; ++i) s += partials[(size_t)slot * K + i];
        lossf[slot] = (float)(s / (double)n);
    }
    __syncthreads();
    if (tid < 8 && active[tid]) {
        int bb = tid;
        float lb = first ? lossf[bb] : lcur[bb];
        lcur[bb] = lb;
        lall[bb] = lb;
        float ub[6];
#pragma unroll
        for (int j = 0; j < 6; ++j) {
            float grad = lossf[(1 + j) * 8 + bb] - lossf[(7 + j) * 8 + bb];
            float u = first ? grad : (mom[bb * 6 + j] * 0.1f + grad);
            mom[bb * 6 + j] = u;
            ub[j] = u;
        }
        float ss2 = 0.0f;
#pragma unroll
        for (int j = 0; j < 6; ++j) ss2 += ub[j] * ub[j];
        float denom = sqrtf(ss2) + 1e-6f;
#pragma unroll
        for (int j = 0; j < 6; ++j) {
            float d = ub[j] / denom;
            ttry[bb * 6 + j] = theta[bb * 6 + j] - ss * d;
        }
    }
}

// ---------------------------------------------------------------------------
// Trial eval + fused update2 tail. reset=1 on the last iteration of a step.
// ---------------------------------------------------------------------------
template<int D, int K>
__global__ __launch_bounds__(256) void trial_kernel(
    const float* __restrict__ srcp, const float* __restrict__ tgt,
    const float* __restrict__ ttry, float* __restrict__ theta,
    float* __restrict__ lcur, int* __restrict__ active,
    double* __restrict__ partials, int* __restrict__ counter, int reset)
{
    constexpr int n = D * D * D;
    __shared__ double red[256];
    __shared__ int lastf;
    const int tid = threadIdx.x;
    const int gb = blockIdx.x;
    const int k = gb % K;
    const int b = gb / K;

    if (active[b]) {
        float th[6];
#pragma unroll
        for (int j = 0; j < 6; ++j) th[j] = ttry[b * 6 + j];
        eval_block<D, K>(srcp, tgt, th, b, k, red);
        if (tid == 0) partials[(size_t)b * K + k] = red[0];
    }

    __threadfence();
    if (tid == 0) lastf = (atomicAdd(counter, 1) == (int)gridDim.x - 1) ? 1 : 0;
    __syncthreads();
    if (!lastf) return;
    if (tid == 0) *counter = 0;

    // ---- elected last block: update2 (32 threads per row b) ----
    const int bb = tid >> 5, j = tid & 31;
    double s = 0.0;
    for (int i = j; i < K; i += 32) s += partials[(size_t)bb * K + i];
    red[tid] = s;
    __syncthreads();
#pragma unroll
    for (int st = 16; st > 0; st >>= 1) {
        if (j < st) red[tid] += red[tid + st];
        __syncthreads();
    }
    if (j == 0) {
        if (active[bb]) {
            float ln = (float)(red[tid] / (double)n);
            if (ln + 1e-4f < lcur[bb]) {
#pragma unroll
                for (int q = 0; q < 6; ++q) theta[bb * 6 + q] = ttry[bb * 6 + q];
                lcur[bb] = ln;
            } else {
                active[bb] = 0;
            }
        }
        if (reset) active[bb] = 1;
    }
}

// ---------------------------------------------------------------------------
// Pool: src-pool into padded layout, tgt-pool linear (round-4 verbatim).
// ---------------------------------------------------------------------------
template<int f>
__global__ void pool_pad_kernel(const float* __restrict__ src, const float* __restrict__ tgt,
                                float* __restrict__ srcp, float* __restrict__ tgtp)
{
    constexpr int Do = 64 / f;
    constexpr int P = Do + 3;
    constexpr int n = 8 * Do * Do * Do;
    int idx = blockIdx.x * blockDim.x + threadIdx.x;
    if (idx >= 2 * n) return;
    bool is_src = idx < n;
    int id = is_src ? idx : idx - n;
    int kk = id % Do;
    int jj = (id / Do) % Do;
    int ii = (id / (Do * Do)) % Do;
    int b  = id / (Do * Do * Do);
    const float* v = (is_src ? src : tgt) + (size_t)b * 262144;
    double s = 0.0;
    for (int p = 0; p < f; ++p)
        for (int q = 0; q < f; ++q)
            for (int r = 0; r < f; ++r)
                s += (double)v[((ii * f + p) * 64 + (jj * f + q)) * 64 + (kk * f + r)];
    float val = (float)(s / (double)(f * f * f));
    if (is_src) srcp[(size_t)b * P * P * P + (((ii + 1) * P + (jj + 1)) * P + (kk + 1))] = val;
    else        tgtp[id] = val;
}

// Copy D=64 src into padded layout (P=67).
__global__ void pad_copy_kernel(const float* __restrict__ src, float* __restrict__ dst)
{
    int idx = blockIdx.x * blockDim.x + threadIdx.x;
    if (idx >= 8 * 262144) return;
    int kk = idx & 63;
    int jj = (idx >> 6) & 63;
    int ii = (idx >> 12) & 63;
    int b  = idx >> 18;
    dst[(size_t)b * 67 * 67 * 67 + (((ii + 1) * 67 + (jj + 1)) * 67 + (kk + 1))] = src[idx];
}

__global__ void init_kernel(const float* __restrict__ theta_in,
                            float* __restrict__ theta_deg,
                            int* __restrict__ active,
                            int* __restrict__ counters)
{
    int t = threadIdx.x;
    if (t < 48) {
        int j = t % 6;
        float d2r = (j < 3) ? PI180F : 1.0f;
        theta_deg[t] = theta_in[t] / d2r;
    }
    if (t < 8) active[t] = 1;
    if (t < 2) counters[t] = 0;
}

__global__ void finalize_kernel(const float* __restrict__ theta0,
                                const float* __restrict__ theta_deg,
                                const float* __restrict__ loss_all,
                                float* __restrict__ out)
{
    int t = threadIdx.x;
    if (t < 48) {
        int j = t % 6;
        float d2r = (j < 3) ? PI180F : 1.0f;
        float td = theta_deg[t] * d2r;
        float dt = td - theta0[t];
        out[t] = theta0[t] + dt;
    } else if (t < 56) {
        out[t] = loss_all[t - 48];
    }
}

// ---------------------------------------------------------------------------
template<int D, int K, int K3>
static void run_level(const float* srcp, const float* tgt,
                      float* theta, float* ttry, float* mom,
                      float* lcur, float* lall, int* active,
                      double* pA, double* pB, int* ctrs, float ss0,
                      hipStream_t stream)
{
    float ssv = ss0;
    for (int s = 0; s < 4; ++s) {
        for (int it = 0; it < 10; ++it) {
            int first = (s == 0 && it == 0) ? 1 : 0;
            int nconf = first ? 13 : 12;
            fd_kernel<D, K><<<nconf * 8 * K, 256, 0, stream>>>(
                srcp, tgt, theta, ttry, mom, lcur, lall, active, pA, &ctrs[0], ssv, first);
            trial_kernel<D, K3><<<8 * K3, 256, 0, stream>>>(
                srcp, tgt, ttry, theta, lcur, active, pB, &ctrs[1], (it == 9) ? 1 : 0);
        }
        ssv *= 0.5f;
    }
}

extern "C" void kernel_launch(void* const* d_in, const int* in_sizes, int n_in,
                              void* d_out, int out_size, void* d_ws, size_t ws_size,
                              hipStream_t stream)
{
    const float* theta0 = (const float*)d_in[0];
    const float* source = (const float*)d_in[1];
    const float* target = (const float*)d_in[2];
    float* out = (float*)d_out;

    char* ws = (char*)d_ws;
    size_t off = 0;
    auto alloc = [&](size_t bytes) -> void* {
        off = (off + 255) & ~(size_t)255;
        void* p = ws + off;
        off += bytes;
        return p;
    };
    float*  theta  = (float*)alloc(48 * 4);
    float*  ttry   = (float*)alloc(48 * 4);
    float*  mom    = (float*)alloc(48 * 4);
    float*  lcur   = (float*)alloc(8 * 4);
    float*  lall   = (float*)alloc(8 * 4);
    int*    active = (int*)alloc(8 * 4);
    int*    ctrs   = (int*)alloc(2 * 4);
    double* pA     = (double*)alloc(104 * 32 * 8);
    double* pB     = (double*)alloc(8 * 128 * 8);
    float*  tgt2   = (float*)alloc((size_t)8 * 32768 * 4);
    float*  tgt4   = (float*)alloc((size_t)8 * 4096 * 4);
    const size_t PS16 = 19 * 19 * 19, PS32 = 35 * 35 * 35, PS64 = 67 * 67 * 67;
    float*  pad16  = (float*)alloc((size_t)8 * PS16 * 4);
    float*  pad32  = (float*)alloc((size_t)8 * PS32 * 4);
    float*  pad64  = (float*)alloc((size_t)8 * PS64 * 4);

    hipMemsetAsync(pad16, 0, (size_t)8 * PS16 * 4, stream);
    hipMemsetAsync(pad32, 0, (size_t)8 * PS32 * 4, stream);
    hipMemsetAsync(pad64, 0, (size_t)8 * PS64 * 4, stream);

    pool_pad_kernel<2><<<(2 * 8 * 32768 + 255) / 256, 256, 0, stream>>>(source, target, pad32, tgt2);
    pool_pad_kernel<4><<<(2 * 8 * 4096 + 255) / 256, 256, 0, stream>>>(source, target, pad16, tgt4);
    pad_copy_kernel<<<(8 * 262144 + 255) / 256, 256, 0, stream>>>(source, pad64);
    init_kernel<<<1, 64, 0, stream>>>(theta0, theta, active, ctrs);

    run_level<16,  2,   8>(pad16, tgt4,   theta, ttry, mom, lcur, lall, active, pA, pB, ctrs, 8.0f, stream);
    run_level<32,  8,  32>(pad32, tgt2,   theta, ttry, mom, lcur, lall, active, pA, pB, ctrs, 4.0f, stream);
    run_level<64, 32, 128>(pad64, target, theta, ttry, mom, lcur, lall, active, pA, pB, ctrs, 2.0f, stream);

    finalize_kernel<<<1, 64, 0, stream>>>(theta0, theta, lall, out);
}

// Round 6
// 963.769 us; speedup vs baseline: 13.8426x; 13.8426x over previous
//
#include <hip/hip_runtime.h>

// np.float32(np.pi / 180)
#define PI180F 0.017453292519943295f

// ---------------------------------------------------------------------------
// Rotation matrix, matching the reference's (Rz @ Ry) @ Rx in fp32.
// ---------------------------------------------------------------------------
__device__ __forceinline__ void compute_R(const float th[6], float R[9], float t[3]) {
    float ax = th[0] * PI180F, ay = th[1] * PI180F, az = th[2] * PI180F;
    float cx = cosf(ax), sx = sinf(ax);
    float cy = cosf(ay), sy = sinf(ay);
    float cz = cosf(az), sz = sinf(az);
    R[0] = cz * cy;  R[1] = (cz * sy) * sx - sz * cx;  R[2] = (cz * sy) * cx + sz * sx;
    R[3] = sz * cy;  R[4] = (sz * sy) * sx + cz * cx;  R[5] = (sz * sy) * cx - cz * sx;
    R[6] = -sy;      R[7] = cy * sx;                   R[8] = cy * cx;
    t[0] = th[3]; t[1] = th[4]; t[2] = th[5];
}

// ---------------------------------------------------------------------------
// Trilinear sample on a zero-padded volume (side P=D+3) — round-4 proven,
// branch-free, bit-identical to the predicated reference form.
// ---------------------------------------------------------------------------
template<int D>
__device__ __forceinline__ float tri_sample_pad(const float* __restrict__ vol,
                                                float c0, float c1, float c2) {
    constexpr int P = D + 3;
    float f0 = floorf(c0), f1 = floorf(c1), f2 = floorf(c2);
    int i0 = (int)f0, i1 = (int)f1, i2 = (int)f2;
    float t0 = c0 - f0, t1 = c1 - f1, t2 = c2 - f2;
    float w0[2] = {1.0f - t0, t0};
    float w1[2] = {1.0f - t1, t1};
    float w2[2] = {1.0f - t2, t2};
    int ip0 = ((unsigned)(i0 + 1) <= (unsigned)D) ? (i0 + 1) : (D + 1);
    int ip1 = ((unsigned)(i1 + 1) <= (unsigned)D) ? (i1 + 1) : (D + 1);
    int ip2 = ((unsigned)(i2 + 1) <= (unsigned)D) ? (i2 + 1) : (D + 1);
    const float* p = vol + ((ip0 * P + ip1) * P + ip2);
    float acc = 0.0f;
    acc += ((w0[0] * w1[0]) * w2[0]) * p[0];
    acc += ((w0[0] * w1[0]) * w2[1]) * p[1];
    acc += ((w0[0] * w1[1]) * w2[0]) * p[P];
    acc += ((w0[0] * w1[1]) * w2[1]) * p[P + 1];
    acc += ((w0[1] * w1[0]) * w2[0]) * p[P * P];
    acc += ((w0[1] * w1[0]) * w2[1]) * p[P * P + 1];
    acc += ((w0[1] * w1[1]) * w2[0]) * p[P * P + P];
    acc += ((w0[1] * w1[1]) * w2[1]) * p[P * P + P + 1];
    return acc;
}

// ---------------------------------------------------------------------------
// Eval body (round-4 verbatim inner loop), block partial left in red[0].
// ---------------------------------------------------------------------------
template<int D, int K>
__device__ __forceinline__ void eval_block(
    const float* __restrict__ srcp, const float* __restrict__ tgt,
    const float th[6], int b, int k, double* __restrict__ red)
{
    constexpr int logD = (D == 64) ? 6 : ((D == 32) ? 5 : 4);
    constexpr int n = D * D * D;
    constexpr int PS = (D + 3) * (D + 3) * (D + 3);
    float R[9], t[3];
    compute_R(th, R, t);

    constexpr int chunk = n / K;
    const int vstart = k * chunk;
    const float step = 2.0f / (float)(D - 1);
    const float scale = (float)(D - 1) * 0.5f;
    const float* s = srcp + (size_t)b * PS;
    const float* g = tgt + (size_t)b * n;

    double acc = 0.0;
    for (int v = vstart + threadIdx.x; v < vstart + chunk; v += 256) {
        int kk = v & (D - 1);
        int jj = (v >> logD) & (D - 1);
        int ii = v >> (2 * logD);
        float x0 = -1.0f + (float)ii * step;
        float x1 = -1.0f + (float)jj * step;
        float x2 = -1.0f + (float)kk * step;
        float p0 = R[0] * x0 + R[1] * x1 + R[2] * x2 + t[0];
        float p1 = R[3] * x0 + R[4] * x1 + R[5] * x2 + t[1];
        float p2 = R[6] * x0 + R[7] * x1 + R[8] * x2 + t[2];
        float c0 = (p0 + 1.0f) * scale;
        float c1 = (p1 + 1.0f) * scale;
        float c2 = (p2 + 1.0f) * scale;
        float w = tri_sample_pad<D>(s, c0, c1, c2);
        float d = w - g[v];
        acc += (double)(d * d);
    }

    red[threadIdx.x] = acc;
    __syncthreads();
#pragma unroll
    for (int st = 128; st > 0; st >>= 1) {
        if (threadIdx.x < st) red[threadIdx.x] += red[threadIdx.x + st];
        __syncthreads();
    }
}

// ---------------------------------------------------------------------------
// FD eval with redundant update2 head. Every block recomputes the previous
// trial's accept/reject for its row from pB (written by the previous kernel
// launch — kernel-boundary visibility, no fences). Designated block
// (c-group 0, k==0) persists state to the OUT slot (double-buffered).
// ---------------------------------------------------------------------------
template<int D, int K>
__global__ __launch_bounds__(256) void fd_kernel(
    const float* __restrict__ srcp, const float* __restrict__ tgt,
    const float* __restrict__ thetaIn, const float* __restrict__ lcurIn,
    const int* __restrict__ activeIn,
    float* __restrict__ thetaOut, float* __restrict__ lcurOut,
    int* __restrict__ activeOut,
    const float* __restrict__ ttry, const double* __restrict__ pB,
    double* __restrict__ partials,
    float ss, int first, int apply, int reset, int k3prev, int nprev)
{
    __shared__ double red[256];
    __shared__ float sth[6];
    __shared__ int sact;
    const int tid = threadIdx.x;
    const int gb = blockIdx.x;
    const int k = gb % K;
    const int e = gb / K;
    const int b = e & 7;
    const int c = first ? (e >> 3) : (e >> 3) + 1;

    if (apply) {
        if (tid < 32) {
            double v = (tid < k3prev) ? pB[b * k3prev + tid] : 0.0;
            v += __shfl_down(v, 16, 32);
            v += __shfl_down(v, 8, 32);
            v += __shfl_down(v, 4, 32);
            v += __shfl_down(v, 2, 32);
            v += __shfl_down(v, 1, 32);
            if (tid == 0) {
                int na = activeIn[b];
                float l = lcurIn[b];
                float th[6];
#pragma unroll
                for (int j = 0; j < 6; ++j) th[j] = thetaIn[b * 6 + j];
                if (na) {
                    float ln = (float)(v / (double)nprev);
                    if (ln + 1e-4f < l) {
#pragma unroll
                        for (int j = 0; j < 6; ++j) th[j] = ttry[b * 6 + j];
                        l = ln;
                    } else {
                        na = 0;
                    }
                }
                if (reset) na = 1;
#pragma unroll
                for (int j = 0; j < 6; ++j) sth[j] = th[j];
                sact = na;
                if (((e >> 3) == 0) && (k == 0)) {
#pragma unroll
                    for (int j = 0; j < 6; ++j) thetaOut[b * 6 + j] = th[j];
                    lcurOut[b] = l;
                    activeOut[b] = na;
                }
            }
        }
        __syncthreads();
    } else {
        if (tid < 6) sth[tid] = thetaIn[b * 6 + tid];
        if (tid == 0) sact = activeIn[b];
        __syncthreads();
    }

    if (!sact) return;
    float th[6];
#pragma unroll
    for (int j = 0; j < 6; ++j) th[j] = sth[j];
    if (c > 0) {
        int j = (c - 1) % 6;
        th[j] += (c <= 6) ? ss : -ss;
    }
    eval_block<D, K>(srcp, tgt, th, b, k, red);
    if (tid == 0) partials[(size_t)(c * 8 + b) * K + k] = red[0];
}

// ---------------------------------------------------------------------------
// Trial eval with redundant update1 head. Every block reduces its row's FD
// partials (13 or 12 slots x K, 32-lane shuffle trees), computes
// grad/momentum/direction/ttry redundantly; k==0 block persists
// mom (double-buffered), ttry, lall (+ lcur when first).
// ---------------------------------------------------------------------------
template<int D, int K3, int K>
__global__ __launch_bounds__(256) void trial_kernel(
    const float* __restrict__ srcp, const float* __restrict__ tgt,
    const float* __restrict__ theta, float* __restrict__ lcur,
    const int* __restrict__ active,
    const float* __restrict__ momIn, float* __restrict__ momOut,
    float* __restrict__ ttry, float* __restrict__ lall,
    const double* __restrict__ pA, double* __restrict__ pB,
    float ss, int first)
{
    constexpr int n = D * D * D;
    __shared__ double red[256];
    __shared__ float lossf[13];
    __shared__ float sttry[6];
    const int tid = threadIdx.x;
    const int gb = blockIdx.x;
    const int k = gb % K3;
    const int b = gb / K3;

    if (!active[b]) {
        // momentum copy-through (reference: buf unchanged where inactive)
        if (k == 0 && tid < 6) momOut[b * 6 + tid] = momIn[b * 6 + tid];
        return;
    }

    const int nconf = first ? 13 : 12;
#pragma unroll
    for (int p = 0; p < 2; ++p) {
        int ci = p * 8 + (tid >> 5);            // group of 32 lanes per slot
        if (ci < nconf) {
            int ca = first ? ci : ci + 1;       // absolute config index
            int kk = tid & 31;
            double v = (kk < K) ? pA[(size_t)(ca * 8 + b) * K + kk] : 0.0;
            v += __shfl_down(v, 16, 32);
            v += __shfl_down(v, 8, 32);
            v += __shfl_down(v, 4, 32);
            v += __shfl_down(v, 2, 32);
            v += __shfl_down(v, 1, 32);
            if (kk == 0) lossf[ca] = (float)(v / (double)n);
        }
    }
    __syncthreads();
    if (tid == 0) {
        float lb = first ? lossf[0] : lcur[b];
        float ub[6];
#pragma unroll
        for (int j = 0; j < 6; ++j) {
            float grad = lossf[1 + j] - lossf[7 + j];
            float u = first ? grad : (momIn[b * 6 + j] * 0.1f + grad);
            ub[j] = u;
        }
        float ss2 = 0.0f;
#pragma unroll
        for (int j = 0; j < 6; ++j) ss2 += ub[j] * ub[j];
        float denom = sqrtf(ss2) + 1e-6f;
#pragma unroll
        for (int j = 0; j < 6; ++j) sttry[j] = theta[b * 6 + j] - ss * (ub[j] / denom);
        if (k == 0) {
            lall[b] = lb;
            if (first) lcur[b] = lb;            // establish base at level start
#pragma unroll
            for (int j = 0; j < 6; ++j) momOut[b * 6 + j] = ub[j];
#pragma unroll
            for (int j = 0; j < 6; ++j) ttry[b * 6 + j] = sttry[j];
        }
    }
    __syncthreads();
    float th[6];
#pragma unroll
    for (int j = 0; j < 6; ++j) th[j] = sttry[j];
    eval_block<D, K3>(srcp, tgt, th, b, k, red);
    if (tid == 0) pB[(size_t)b * K3 + k] = red[0];
}

// ---------------------------------------------------------------------------
// Finalize: applies the very last update2 (level 2, K3=32, n=262144) and
// writes theta-out + loss.
// ---------------------------------------------------------------------------
__global__ __launch_bounds__(256) void finalize_kernel(
    const float* __restrict__ theta0,
    const float* __restrict__ theta, const float* __restrict__ lcur,
    const int* __restrict__ active, const float* __restrict__ ttry,
    const double* __restrict__ pB, const float* __restrict__ lall,
    float* __restrict__ out)
{
    __shared__ double rs[8];
    __shared__ float fth[48];
    const int tid = threadIdx.x;
    const int r = tid >> 5, l = tid & 31;
    {
        double v = pB[r * 32 + l];
        v += __shfl_down(v, 16, 32);
        v += __shfl_down(v, 8, 32);
        v += __shfl_down(v, 4, 32);
        v += __shfl_down(v, 2, 32);
        v += __shfl_down(v, 1, 32);
        if (l == 0) rs[r] = v;
    }
    __syncthreads();
    if (tid < 8) {
        int b = tid;
        bool acc = false;
        if (active[b]) {
            float ln = (float)(rs[b] / 262144.0);
            acc = (ln + 1e-4f < lcur[b]);
        }
        for (int j = 0; j < 6; ++j)
            fth[b * 6 + j] = acc ? ttry[b * 6 + j] : theta[b * 6 + j];
    }
    __syncthreads();
    if (tid < 48) {
        int j = tid % 6;
        float d2r = (j < 3) ? PI180F : 1.0f;
        float td = fth[tid] * d2r;
        out[tid] = theta0[tid] + (td - theta0[tid]);
    } else if (tid < 56) {
        out[tid] = lall[tid - 48];
    }
}

// ---------------------------------------------------------------------------
// Pool: src-pool into padded layout, tgt-pool linear (round-4 verbatim).
// ---------------------------------------------------------------------------
template<int f>
__global__ void pool_pad_kernel(const float* __restrict__ src, const float* __restrict__ tgt,
                                float* __restrict__ srcp, float* __restrict__ tgtp)
{
    constexpr int Do = 64 / f;
    constexpr int P = Do + 3;
    constexpr int n = 8 * Do * Do * Do;
    int idx = blockIdx.x * blockDim.x + threadIdx.x;
    if (idx >= 2 * n) return;
    bool is_src = idx < n;
    int id = is_src ? idx : idx - n;
    int kk = id % Do;
    int jj = (id / Do) % Do;
    int ii = (id / (Do * Do)) % Do;
    int b  = id / (Do * Do * Do);
    const float* v = (is_src ? src : tgt) + (size_t)b * 262144;
    double s = 0.0;
    for (int p = 0; p < f; ++p)
        for (int q = 0; q < f; ++q)
            for (int r = 0; r < f; ++r)
                s += (double)v[((ii * f + p) * 64 + (jj * f + q)) * 64 + (kk * f + r)];
    float val = (float)(s / (double)(f * f * f));
    if (is_src) srcp[(size_t)b * P * P * P + (((ii + 1) * P + (jj + 1)) * P + (kk + 1))] = val;
    else        tgtp[id] = val;
}

// Copy D=64 src into padded layout (P=67).
__global__ void pad_copy_kernel(const float* __restrict__ src, float* __restrict__ dst)
{
    int idx = blockIdx.x * blockDim.x + threadIdx.x;
    if (idx >= 8 * 262144) return;
    int kk = idx & 63;
    int jj = (idx >> 6) & 63;
    int ii = (idx >> 12) & 63;
    int b  = idx >> 18;
    dst[(size_t)b * 67 * 67 * 67 + (((ii + 1) * 67 + (jj + 1)) * 67 + (kk + 1))] = src[idx];
}

__global__ void init_kernel(const float* __restrict__ theta_in,
                            float* __restrict__ theta_deg,
                            float* __restrict__ lcur,
                            int* __restrict__ active)
{
    int t = threadIdx.x;
    if (t < 48) {
        int j = t % 6;
        float d2r = (j < 3) ? PI180F : 1.0f;
        theta_deg[t] = theta_in[t] / d2r;
    }
    if (t < 8) { active[t] = 1; lcur[t] = 0.0f; }
}

// ---------------------------------------------------------------------------
template<int D, int K, int K3>
static void run_level(const float* srcp, const float* tgt,
                      float* const thetaS[2], float* const lcurS[2], int* const activeS[2],
                      float* const momS[2], float* ttry, float* lall,
                      double* pA, double* pB,
                      int L, int& scur, int& mcur, int k3prevLvl, int nprevLvl,
                      float ss0, hipStream_t stream)
{
    float ssv = ss0;
    for (int s = 0; s < 4; ++s) {
        for (int it = 0; it < 10; ++it) {
            int first = (s == 0 && it == 0) ? 1 : 0;
            int apply = !(L == 0 && first);
            int reset = (it == 0) ? 1 : 0;
            int k3p = first ? k3prevLvl : K3;
            int np  = first ? nprevLvl  : D * D * D;
            int nconf = first ? 13 : 12;
            int so = apply ? (scur ^ 1) : scur;
            fd_kernel<D, K><<<nconf * 8 * K, 256, 0, stream>>>(
                srcp, tgt,
                thetaS[scur], lcurS[scur], activeS[scur],
                thetaS[so], lcurS[so], activeS[so],
                ttry, pB, pA, ssv, first, apply, reset, k3p, np);
            if (apply) scur ^= 1;
            trial_kernel<D, K3, K><<<8 * K3, 256, 0, stream>>>(
                srcp, tgt,
                thetaS[scur], lcurS[scur], activeS[scur],
                momS[mcur], momS[mcur ^ 1], ttry, lall, pA, pB, ssv, first);
            mcur ^= 1;
        }
        ssv *= 0.5f;
    }
}

extern "C" void kernel_launch(void* const* d_in, const int* in_sizes, int n_in,
                              void* d_out, int out_size, void* d_ws, size_t ws_size,
                              hipStream_t stream)
{
    const float* theta0 = (const float*)d_in[0];
    const float* source = (const float*)d_in[1];
    const float* target = (const float*)d_in[2];
    float* out = (float*)d_out;

    char* ws = (char*)d_ws;
    size_t off = 0;
    auto alloc = [&](size_t bytes) -> void* {
        off = (off + 255) & ~(size_t)255;
        void* p = ws + off;
        off += bytes;
        return p;
    };
    float* thetaS[2] = { (float*)alloc(48 * 4), (float*)alloc(48 * 4) };
    float* lcurS[2]  = { (float*)alloc(8 * 4),  (float*)alloc(8 * 4)  };
    int*   activeS[2]= { (int*)alloc(8 * 4),    (int*)alloc(8 * 4)    };
    float* momS[2]   = { (float*)alloc(48 * 4), (float*)alloc(48 * 4) };
    float* ttry  = (float*)alloc(48 * 4);
    float* lall  = (float*)alloc(8 * 4);
    double* pA   = (double*)alloc(13 * 8 * 32 * 8);
    double* pB   = (double*)alloc(8 * 32 * 8);
    float* tgt2  = (float*)alloc((size_t)8 * 32768 * 4);
    float* tgt4  = (float*)alloc((size_t)8 * 4096 * 4);
    const size_t PS16 = 19 * 19 * 19, PS32 = 35 * 35 * 35, PS64 = 67 * 67 * 67;
    float* pad16 = (float*)alloc((size_t)8 * PS16 * 4);
    float* pad32 = (float*)alloc((size_t)8 * PS32 * 4);
    float* pad64 = (float*)alloc((size_t)8 * PS64 * 4);

    hipMemsetAsync(pad16, 0, (size_t)8 * PS16 * 4, stream);
    hipMemsetAsync(pad32, 0, (size_t)8 * PS32 * 4, stream);
    hipMemsetAsync(pad64, 0, (size_t)8 * PS64 * 4, stream);

    pool_pad_kernel<2><<<(2 * 8 * 32768 + 255) / 256, 256, 0, stream>>>(source, target, pad32, tgt2);
    pool_pad_kernel<4><<<(2 * 8 * 4096 + 255) / 256, 256, 0, stream>>>(source, target, pad16, tgt4);
    pad_copy_kernel<<<(8 * 262144 + 255) / 256, 256, 0, stream>>>(source, pad64);
    init_kernel<<<1, 64, 0, stream>>>(theta0, thetaS[0], lcurS[0], activeS[0]);

    int scur = 0, mcur = 0;
    run_level<16,  2, 16>(pad16, tgt4,   thetaS, lcurS, activeS, momS, ttry, lall,
                          pA, pB, 0, scur, mcur, 16, 4096, 8.0f, stream);
    run_level<32,  8, 32>(pad32, tgt2,   thetaS, lcurS, activeS, momS, ttry, lall,
                          pA, pB, 1, scur, mcur, 16, 4096, 4.0f, stream);
    run_level<64, 32, 32>(pad64, target, thetaS, lcurS, activeS, momS, ttry, lall,
                          pA, pB, 2, scur, mcur, 32, 32768, 2.0f, stream);

    finalize_kernel<<<1, 256, 0, stream>>>(
        theta0, thetaS[scur], lcurS[scur], activeS[scur], ttry, pB, lall, out);
}